// Round 4
// baseline (84.873 us; speedup 1.0000x reference)
//
#include <hip/hip_runtime.h>

#define HH 256
#define WW 256
#define CC 64
#define BB 2
#define KK2 9
#define HWSZ (HH * WW)
#define NQ (CC / 4)            // 16 float4 per NHWC pixel

// ---------------- transpose: x[b][c][h][w] -> xT[b][h][w][c] ----------------
__global__ __launch_bounds__(256, 4) void transpose_nchw_to_nhwc(
    const float* __restrict__ x, float* __restrict__ xT)
{
    __shared__ float tile[CC][65];
    const int row = blockIdx.x;
    const int h   = row & (HH - 1);
    const int b   = row >> 8;
    const int w0  = blockIdx.y * 64;
    const int lw  = threadIdx.x & 63;
    const int lr  = threadIdx.x >> 6;

    const float* xp = x + (size_t)b * CC * HWSZ + h * WW + w0;
#pragma unroll
    for (int p = 0; p < 16; ++p) {
        int c = p * 4 + lr;
        tile[c][lw] = xp[(size_t)c * HWSZ + lw];
    }
    __syncthreads();
    float* xo = xT + ((size_t)(b * HH + h) * WW + w0) * CC;
#pragma unroll
    for (int p = 0; p < 16; ++p) {
        int wl = p * 4 + lr;
        xo[wl * CC + lw] = tile[lw][wl];
    }
}

// ---------------- main: NHWC gather, all 64 channels per block ----------------
// 2048 blocks x 256 threads; block = 64 pixels x all channels.
// lane: p = t>>2 (pixel), jq = t&3 (channel quad phase).
// XCD-chunked bijective swizzle keeps each row band in one XCD's L2.
// Latency plan: 27 offset/mask loads preloaded; per k all 16 gathers are
// issued before any FMA (explicit float4 buffers -> counted vmcnt waits).
__global__ __launch_bounds__(256, 4) void dcn_nhwc3(
    const float4* __restrict__ xT,
    const float* __restrict__ offset,
    const float* __restrict__ mask,
    const float* __restrict__ weight,
    float* __restrict__ out)
{
    const int nblocks = BB * HH * (WW / 64);        // 2048
    int flat = blockIdx.x;
    int sb   = (flat & 7) * (nblocks >> 3) + (flat >> 3);
    int wchunk = sb & 3;
    int row    = sb >> 2;
    const int h = row & (HH - 1);
    const int b = row >> 8;

    const int t  = threadIdx.x;
    const int jq = t & 3;
    const int p  = t >> 2;
    const int w  = (wchunk << 6) + p;
    const int hw = h * WW + w;

    const float* offb  = offset + (size_t)b * 2 * KK2 * HWSZ + hw;
    const float* maskb = mask   + (size_t)b * KK2 * HWSZ + hw;
    const float4* xb   = xT + (size_t)b * HWSZ * NQ;

    // ---- preload all per-pixel bilinear params (independent loads) ----
    float offy[KK2], offx[KK2], mv[KK2];
#pragma unroll
    for (int k = 0; k < KK2; ++k) {
        offy[k] = offb[(2 * k)     * HWSZ];
        offx[k] = offb[(2 * k + 1) * HWSZ];
    }
#pragma unroll
    for (int k = 0; k < KK2; ++k) {
        mv[k] = maskb[k * HWSZ] * weight[k];
    }

    float4 acc[4];
#pragma unroll
    for (int j = 0; j < 4; ++j) acc[j] = make_float4(0.f, 0.f, 0.f, 0.f);

#pragma unroll
    for (int k = 0; k < KK2; ++k) {
        const int ki = k / 3;
        const int kj = k - 3 * ki;

        float py = (float)(h - 1 + ki) + offy[k];
        float px = (float)(w - 1 + kj) + offx[k];
        float y0f = floorf(py), x0f = floorf(px);
        float ly = py - y0f, lx = px - x0f;
        float hy = 1.f - ly, hx = 1.f - lx;
        int y0 = (int)y0f, x0 = (int)x0f;
        int y1 = y0 + 1,   x1 = x0 + 1;

        bool vy0 = (unsigned)y0 < (unsigned)HH;
        bool vy1 = (unsigned)y1 < (unsigned)HH;
        bool vx0 = (unsigned)x0 < (unsigned)WW;
        bool vx1 = (unsigned)x1 < (unsigned)WW;
        int y0c = min(max(y0, 0), HH - 1);
        int y1c = min(max(y1, 0), HH - 1);
        int x0c = min(max(x0, 0), WW - 1);
        int x1c = min(max(x1, 0), WW - 1);

        float w00 = hy * hx * mv[k] * (float)(vy0 && vx0);
        float w01 = hy * lx * mv[k] * (float)(vy0 && vx1);
        float w10 = ly * hx * mv[k] * (float)(vy1 && vx0);
        float w11 = ly * lx * mv[k] * (float)(vy1 && vx1);

        int i00 = (y0c * WW + x0c) * NQ + jq;
        int i01 = (y0c * WW + x1c) * NQ + jq;
        int i10 = (y1c * WW + x0c) * NQ + jq;
        int i11 = (y1c * WW + x1c) * NQ + jq;

        // ---- issue ALL 16 gathers before any use ----
        float4 v00[4], v01[4], v10[4], v11[4];
#pragma unroll
        for (int j = 0; j < 4; ++j) v00[j] = xb[i00 + 4 * j];
#pragma unroll
        for (int j = 0; j < 4; ++j) v01[j] = xb[i01 + 4 * j];
#pragma unroll
        for (int j = 0; j < 4; ++j) v10[j] = xb[i10 + 4 * j];
#pragma unroll
        for (int j = 0; j < 4; ++j) v11[j] = xb[i11 + 4 * j];

#pragma unroll
        for (int j = 0; j < 4; ++j) {
            acc[j].x = fmaf(w00, v00[j].x, fmaf(w01, v01[j].x, fmaf(w10, v10[j].x, fmaf(w11, v11[j].x, acc[j].x))));
            acc[j].y = fmaf(w00, v00[j].y, fmaf(w01, v01[j].y, fmaf(w10, v10[j].y, fmaf(w11, v11[j].y, acc[j].y))));
            acc[j].z = fmaf(w00, v00[j].z, fmaf(w01, v01[j].z, fmaf(w10, v10[j].z, fmaf(w11, v11[j].z, acc[j].z))));
            acc[j].w = fmaf(w00, v00[j].w, fmaf(w01, v01[j].w, fmaf(w10, v10[j].w, fmaf(w11, v11[j].w, acc[j].w))));
        }
    }

    float* ob = out + (size_t)b * CC * HWSZ + (size_t)(jq << 2) * HWSZ + hw;
#pragma unroll
    for (int j = 0; j < 4; ++j) {
        ob[(16 * j + 0) * HWSZ] = acc[j].x;
        ob[(16 * j + 1) * HWSZ] = acc[j].y;
        ob[(16 * j + 2) * HWSZ] = acc[j].z;
        ob[(16 * j + 3) * HWSZ] = acc[j].w;
    }
}

// ---------------- fallback (NCHW direct) ----------------
__global__ __launch_bounds__(256, 4) void dcn_kernel(
    const float* __restrict__ x,
    const float* __restrict__ offset,
    const float* __restrict__ mask,
    const float* __restrict__ weight,
    float* __restrict__ out)
{
    const int w   = threadIdx.x;
    const int row = blockIdx.x;
    const int h   = row & (HH - 1);
    const int b   = row >> 8;
    const int c0  = blockIdx.y * 16;
    const int hw  = h * WW + w;

    const float* offb  = offset + (size_t)b * 2 * KK2 * HWSZ + hw;
    const float* maskb = mask   + (size_t)b * KK2 * HWSZ + hw;
    const float* xb0   = x      + ((size_t)b * CC + c0) * HWSZ;

    float acc[16];
#pragma unroll
    for (int c = 0; c < 16; ++c) acc[c] = 0.f;

    for (int k = 0; k < KK2; ++k) {
        const int ki = k / 3;
        const int kj = k - 3 * ki;
        float offy = offb[(2 * k)     * HWSZ];
        float offx = offb[(2 * k + 1) * HWSZ];
        float mval = maskb[k * HWSZ] * weight[k];

        float py = (float)(h - 1 + ki) + offy;
        float px = (float)(w - 1 + kj) + offx;
        float y0f = floorf(py), x0f = floorf(px);
        float ly = py - y0f, lx = px - x0f;
        float hy = 1.f - ly, hx = 1.f - lx;
        int y0 = (int)y0f, x0 = (int)x0f;
        int y1 = y0 + 1,   x1 = x0 + 1;

        bool vy0 = (unsigned)y0 < (unsigned)HH;
        bool vy1 = (unsigned)y1 < (unsigned)HH;
        bool vx0 = (unsigned)x0 < (unsigned)WW;
        bool vx1 = (unsigned)x1 < (unsigned)WW;
        int y0c = min(max(y0, 0), HH - 1);
        int y1c = min(max(y1, 0), HH - 1);
        int x0c = min(max(x0, 0), WW - 1);
        int x1c = min(max(x1, 0), WW - 1);

        float w00 = hy * hx * mval * (float)(vy0 && vx0);
        float w01 = hy * lx * mval * (float)(vy0 && vx1);
        float w10 = ly * hx * mval * (float)(vy1 && vx0);
        float w11 = ly * lx * mval * (float)(vy1 && vx1);

        int i00 = y0c * WW + x0c;
        int i01 = y0c * WW + x1c;
        int i10 = y1c * WW + x0c;
        int i11 = y1c * WW + x1c;

        const float* xb = xb0;
#pragma unroll
        for (int c = 0; c < 16; ++c) {
            acc[c] = fmaf(w00, xb[i00],
                     fmaf(w01, xb[i01],
                     fmaf(w10, xb[i10],
                     fmaf(w11, xb[i11], acc[c]))));
            xb += HWSZ;
        }
    }

    float* ob = out + ((size_t)b * CC + c0) * HWSZ + hw;
#pragma unroll
    for (int c = 0; c < 16; ++c) ob[c * HWSZ] = acc[c];
}

extern "C" void kernel_launch(void* const* d_in, const int* in_sizes, int n_in,
                              void* d_out, int out_size, void* d_ws, size_t ws_size,
                              hipStream_t stream) {
    const float* x      = (const float*)d_in[0];
    const float* offset = (const float*)d_in[1];
    const float* mask   = (const float*)d_in[2];
    const float* weight = (const float*)d_in[3];
    float* out = (float*)d_out;

    const size_t xT_bytes = (size_t)BB * CC * HWSZ * sizeof(float);
    if (ws_size >= xT_bytes) {
        float* xT = (float*)d_ws;
        dim3 tgrid(BB * HH, WW / 64);
        transpose_nchw_to_nhwc<<<tgrid, 256, 0, stream>>>(x, xT);
        dcn_nhwc3<<<BB * HH * (WW / 64), 256, 0, stream>>>(
            (const float4*)xT, offset, mask, weight, out);
    } else {
        dim3 grid(BB * HH, CC / 16);
        dcn_kernel<<<grid, 256, 0, stream>>>(x, offset, mask, weight, out);
    }
}

// Round 5
// 52.390 us; speedup vs baseline: 1.6200x; 1.6200x over previous
//
#include <hip/hip_runtime.h>
#include <hip/hip_fp16.h>

#define HH 256
#define WW 256
#define CC 64
#define BB 2
#define KK2 9
#define HWSZ (HH * WW)

// ---------------- transpose+convert: x[b][c][h][w] f32 -> xT[b][h][w][c] f16 ----------------
__global__ __launch_bounds__(256, 4) void transpose_nchw_to_nhwc_f16(
    const float* __restrict__ x, __half* __restrict__ xT)
{
    __shared__ float tile[CC][65];
    const int row = blockIdx.x;
    const int h   = row & (HH - 1);
    const int b   = row >> 8;
    const int w0  = blockIdx.y * 64;
    const int lw  = threadIdx.x & 63;
    const int lr  = threadIdx.x >> 6;

    const float* xp = x + (size_t)b * CC * HWSZ + h * WW + w0;
#pragma unroll
    for (int p = 0; p < 16; ++p) {
        int c = p * 4 + lr;
        tile[c][lw] = xp[(size_t)c * HWSZ + lw];
    }
    __syncthreads();
    __half* xo = xT + ((size_t)(b * HH + h) * WW + w0) * CC;
#pragma unroll
    for (int p = 0; p < 16; ++p) {
        int wl = p * 4 + lr;
        xo[wl * CC + lw] = __float2half(tile[lw][wl]);
    }
}

// ---------------- main: fp16-NHWC gather, all 64 channels per block ----------------
// 2048 blocks x 256 threads = 8 blocks/CU fully resident (launch_bounds(256,8)).
// lane: p = t>>2 (pixel 0..63), jq = t&3. Lane owns channels {j*32 + jq*8 + e}.
// Per corner per j: one 16B load (8 halves) -> quad of lanes covers one 64B line.
__global__ __launch_bounds__(256, 8) void dcn_nhwc_f16(
    const __half* __restrict__ xT,
    const float* __restrict__ offset,
    const float* __restrict__ mask,
    const float* __restrict__ weight,
    float* __restrict__ out)
{
    const int nblocks = BB * HH * (WW / 64);        // 2048
    int flat = blockIdx.x;
    int sb   = (flat & 7) * (nblocks >> 3) + (flat >> 3);   // bijective XCD chunk
    int wchunk = sb & 3;
    int row    = sb >> 2;
    const int h = row & (HH - 1);
    const int b = row >> 8;

    const int t  = threadIdx.x;
    const int jq = t & 3;
    const int p  = t >> 2;
    const int w  = (wchunk << 6) + p;
    const int hw = h * WW + w;

    const float* offb  = offset + (size_t)b * 2 * KK2 * HWSZ + hw;
    const float* maskb = mask   + (size_t)b * KK2 * HWSZ + hw;
    const __half* xb   = xT + (size_t)b * HWSZ * CC + (jq << 3);

    float acc[2][8];
#pragma unroll
    for (int j = 0; j < 2; ++j)
#pragma unroll
        for (int e = 0; e < 8; ++e) acc[j][e] = 0.f;

#pragma unroll
    for (int k = 0; k < KK2; ++k) {
        const int ki = k / 3;
        const int kj = k - 3 * ki;
        float offy = offb[(2 * k)     * HWSZ];
        float offx = offb[(2 * k + 1) * HWSZ];
        float mval = maskb[k * HWSZ] * weight[k];

        float py = (float)(h - 1 + ki) + offy;
        float px = (float)(w - 1 + kj) + offx;
        float y0f = floorf(py), x0f = floorf(px);
        float ly = py - y0f, lx = px - x0f;
        float hy = 1.f - ly, hx = 1.f - lx;
        int y0 = (int)y0f, x0 = (int)x0f;
        int y1 = y0 + 1,   x1 = x0 + 1;

        bool vy0 = (unsigned)y0 < (unsigned)HH;
        bool vy1 = (unsigned)y1 < (unsigned)HH;
        bool vx0 = (unsigned)x0 < (unsigned)WW;
        bool vx1 = (unsigned)x1 < (unsigned)WW;
        int y0c = min(max(y0, 0), HH - 1);
        int y1c = min(max(y1, 0), HH - 1);
        int x0c = min(max(x0, 0), WW - 1);
        int x1c = min(max(x1, 0), WW - 1);

        float w00 = hy * hx * mval * (float)(vy0 && vx0);
        float w01 = hy * lx * mval * (float)(vy0 && vx1);
        float w10 = ly * hx * mval * (float)(vy1 && vx0);
        float w11 = ly * lx * mval * (float)(vy1 && vx1);

        // half-index of each corner pixel (channel base folded into xb)
        int i00 = (y0c * WW + x0c) << 6;
        int i01 = (y0c * WW + x1c) << 6;
        int i10 = (y1c * WW + x0c) << 6;
        int i11 = (y1c * WW + x1c) << 6;

#pragma unroll
        for (int j = 0; j < 2; ++j) {
            const int jo = j << 5;   // +32 halves for second channel half
            const __half2* q00 = (const __half2*)(xb + i00 + jo);
            const __half2* q01 = (const __half2*)(xb + i01 + jo);
            const __half2* q10 = (const __half2*)(xb + i10 + jo);
            const __half2* q11 = (const __half2*)(xb + i11 + jo);
#pragma unroll
            for (int u = 0; u < 4; ++u) {
                float2 a00 = __half22float2(q00[u]);
                float2 a01 = __half22float2(q01[u]);
                float2 a10 = __half22float2(q10[u]);
                float2 a11 = __half22float2(q11[u]);
                acc[j][2*u+0] = fmaf(w00, a00.x, fmaf(w01, a01.x, fmaf(w10, a10.x, fmaf(w11, a11.x, acc[j][2*u+0]))));
                acc[j][2*u+1] = fmaf(w00, a00.y, fmaf(w01, a01.y, fmaf(w10, a10.y, fmaf(w11, a11.y, acc[j][2*u+1]))));
            }
        }
    }

    // channel of acc[j][e] is j*32 + jq*8 + e
    float* ob = out + (size_t)b * CC * HWSZ + (size_t)(jq << 3) * HWSZ + hw;
#pragma unroll
    for (int j = 0; j < 2; ++j)
#pragma unroll
        for (int e = 0; e < 8; ++e)
            ob[(j * 32 + e) * HWSZ] = acc[j][e];
}

// ---------------- fallback (NCHW direct) ----------------
__global__ __launch_bounds__(256, 4) void dcn_kernel(
    const float* __restrict__ x,
    const float* __restrict__ offset,
    const float* __restrict__ mask,
    const float* __restrict__ weight,
    float* __restrict__ out)
{
    const int w   = threadIdx.x;
    const int row = blockIdx.x;
    const int h   = row & (HH - 1);
    const int b   = row >> 8;
    const int c0  = blockIdx.y * 16;
    const int hw  = h * WW + w;

    const float* offb  = offset + (size_t)b * 2 * KK2 * HWSZ + hw;
    const float* maskb = mask   + (size_t)b * KK2 * HWSZ + hw;
    const float* xb0   = x      + ((size_t)b * CC + c0) * HWSZ;

    float acc[16];
#pragma unroll
    for (int c = 0; c < 16; ++c) acc[c] = 0.f;

    for (int k = 0; k < KK2; ++k) {
        const int ki = k / 3;
        const int kj = k - 3 * ki;
        float offy = offb[(2 * k)     * HWSZ];
        float offx = offb[(2 * k + 1) * HWSZ];
        float mval = maskb[k * HWSZ] * weight[k];

        float py = (float)(h - 1 + ki) + offy;
        float px = (float)(w - 1 + kj) + offx;
        float y0f = floorf(py), x0f = floorf(px);
        float ly = py - y0f, lx = px - x0f;
        float hy = 1.f - ly, hx = 1.f - lx;
        int y0 = (int)y0f, x0 = (int)x0f;
        int y1 = y0 + 1,   x1 = x0 + 1;

        bool vy0 = (unsigned)y0 < (unsigned)HH;
        bool vy1 = (unsigned)y1 < (unsigned)HH;
        bool vx0 = (unsigned)x0 < (unsigned)WW;
        bool vx1 = (unsigned)x1 < (unsigned)WW;
        int y0c = min(max(y0, 0), HH - 1);
        int y1c = min(max(y1, 0), HH - 1);
        int x0c = min(max(x0, 0), WW - 1);
        int x1c = min(max(x1, 0), WW - 1);

        float w00 = hy * hx * mval * (float)(vy0 && vx0);
        float w01 = hy * lx * mval * (float)(vy0 && vx1);
        float w10 = ly * hx * mval * (float)(vy1 && vx0);
        float w11 = ly * lx * mval * (float)(vy1 && vx1);

        int i00 = y0c * WW + x0c;
        int i01 = y0c * WW + x1c;
        int i10 = y1c * WW + x0c;
        int i11 = y1c * WW + x1c;

        const float* xb = xb0;
#pragma unroll
        for (int c = 0; c < 16; ++c) {
            acc[c] = fmaf(w00, xb[i00],
                     fmaf(w01, xb[i01],
                     fmaf(w10, xb[i10],
                     fmaf(w11, xb[i11], acc[c]))));
            xb += HWSZ;
        }
    }

    float* ob = out + ((size_t)b * CC + c0) * HWSZ + hw;
#pragma unroll
    for (int c = 0; c < 16; ++c) ob[c * HWSZ] = acc[c];
}

extern "C" void kernel_launch(void* const* d_in, const int* in_sizes, int n_in,
                              void* d_out, int out_size, void* d_ws, size_t ws_size,
                              hipStream_t stream) {
    const float* x      = (const float*)d_in[0];
    const float* offset = (const float*)d_in[1];
    const float* mask   = (const float*)d_in[2];
    const float* weight = (const float*)d_in[3];
    float* out = (float*)d_out;

    const size_t xT_bytes = (size_t)BB * CC * HWSZ * sizeof(__half);
    if (ws_size >= xT_bytes) {
        __half* xT = (__half*)d_ws;
        dim3 tgrid(BB * HH, WW / 64);
        transpose_nchw_to_nhwc_f16<<<tgrid, 256, 0, stream>>>(x, xT);
        dcn_nhwc_f16<<<BB * HH * (WW / 64), 256, 0, stream>>>(
            xT, offset, mask, weight, out);
    } else {
        dim3 grid(BB * HH, CC / 16);
        dcn_kernel<<<grid, 256, 0, stream>>>(x, offset, mask, weight, out);
    }
}